// Round 6
// baseline (346.912 us; speedup 1.0000x reference)
//
#include <hip/hip_runtime.h>
#include <stdint.h>

typedef float f32x4 __attribute__((ext_vector_type(4)));
typedef float f32x16 __attribute__((ext_vector_type(16)));
typedef __bf16 bf16x8 __attribute__((ext_vector_type(8)));
typedef unsigned short us8 __attribute__((ext_vector_type(8)));
typedef unsigned short us4 __attribute__((ext_vector_type(4)));
typedef unsigned int u32;

#define MFMA16(A, B, C) __builtin_amdgcn_mfma_f32_16x16x32_bf16( \
    __builtin_bit_cast(bf16x8, (A)), __builtin_bit_cast(bf16x8, (B)), (C), 0, 0, 0)
#define MFMA32(A, B, C) __builtin_amdgcn_mfma_f32_32x32x16_bf16( \
    __builtin_bit_cast(bf16x8, (A)), __builtin_bit_cast(bf16x8, (B)), (C), 0, 0, 0)

__device__ __forceinline__ unsigned short f2bf(float f) {
  u32 u = __builtin_bit_cast(u32, f);
  u = u + 0x7fffu + ((u >> 16) & 1u);   // RNE
  return (unsigned short)(u >> 16);
}
__device__ __forceinline__ float bf2f(unsigned short b) {
  u32 u = ((u32)b) << 16;
  return __builtin_bit_cast(float, u);
}
// async global->LDS, 16B per lane. LDS dest must be wave-uniform base (HW adds lane*16).
__device__ __forceinline__ void gload16(const void* g, void* lds) {
  __builtin_amdgcn_global_load_lds((const __attribute__((address_space(1))) u32*)g,
                                   (__attribute__((address_space(3))) u32*)lds, 16, 0, 0);
}

// ---------------- fp32 -> bf16 conversion of x and weights ----------------
__global__ __launch_bounds__(256) void convert_all(
    const float* __restrict__ x, const float* __restrict__ wq, const float* __restrict__ wk,
    const float* __restrict__ wv, const float* __restrict__ wo,
    unsigned short* __restrict__ xb, unsigned short* __restrict__ wcat,
    unsigned short* __restrict__ wob) {
  int tid = blockIdx.x * 256 + threadIdx.x;
  int nth = gridDim.x * 256;
  const float* srcs[5] = {x, wq, wk, wv, wo};
  unsigned short* dsts[5] = {xb, wcat, wcat + 4194304, wcat + 8388608, wob};
  const int n4s[5] = {2097152, 1048576, 1048576, 1048576, 1048576};
#pragma unroll
  for (int sg = 0; sg < 5; ++sg) {
    const float4* s = (const float4*)srcs[sg];
    us4* d = (us4*)dsts[sg];
    int n4 = n4s[sg];
    for (int i = tid; i < n4; i += nth) {
      float4 v = s[i];
      us4 o;
      o[0] = f2bf(v.x); o[1] = f2bf(v.y); o[2] = f2bf(v.z); o[3] = f2bf(v.w);
      d[i] = o;
    }
  }
}

// ---------------- residency-2 bf16 GEMM via 32x32x16 MFMA, C = A * B^T --------
// BM=128, BN=256, BK=32; 512 thr = 8 waves (2M x 4N); per-wave 64x64 via 32x32x16
// (acc = 2x2 f32x16 = 64 VGPR -> total <=128 -> 2 blocks/CU at launch_bounds(512,4)).
// LDS: 3 buffers x (A 8KB + B 16KB) = 72KB -> 2 blocks/CU (144KB).
// K-major subtiled planes [kb][row][16B] (conflict-free, proven R3); mfma32 frag:
// A/B row = lane&31, k = (lane>>5)*8+e; C/D col=lane&31, row=(r&3)+8*(r>>2)+4*(lane>>5).
// Loop: 1 barrier + 1 vmcnt per K-step. Distance-2 prefetch: iter t stages tile
// t+2 into buf[(t+2)%3] (last read at iter t-1, >=1 barrier ago); VMW(3) after
// MFMA confirms tile t+1 (3 loads of t+2 stay in flight; never vmcnt(0) until tail).
// Residency-2 means one block's MFMA covers the other's stalls (m114 overlap).
template <int EPI>
__global__ __launch_bounds__(512, 4) void gemm32(
    const unsigned short* __restrict__ A, const unsigned short* __restrict__ B,
    int nTN, int N,
    float* __restrict__ outF, const float* __restrict__ bias,
    unsigned short* __restrict__ qb, unsigned short* __restrict__ kb,
    unsigned short* __restrict__ vtb, const float* __restrict__ bq,
    const float* __restrict__ bv) {
  constexpr int KT = 64;  // K=2048 / BK=32
  __shared__ alignas(16) char L[3 * 24576];
  char* Lp = L;
  int bid = (int)blockIdx.x, nwg = (int)gridDim.x;
  {  // XCD-aware swizzle; grids are multiples of 8 (768, 256)
    int qq = nwg >> 3;
    int xcd = bid & 7, idx = bid >> 3;
    bid = xcd * qq + idx;
  }
  int tm = bid / nTN, tn = bid % nTN;
  int t = (int)threadIdx.x, l = t & 63, w = t >> 6;
  int hi = l >> 5, l31 = l & 31;
  int wr = w >> 2, wc = w & 3;   // 2M x 4N wave grid, wave tile 64x64
  // staging: A 8KB/K-step = 1 gload/wave; B 16KB = 2 gload/wave.
  // A flat slot w*1024: plane w>>1, rows (w&1)*64 + l.
  const unsigned short* pAl =
      A + (size_t)(tm * 128 + (w & 1) * 64 + l) * 2048 + (w >> 1) * 8;
  // B flat slots (2w+i)*1024: plane idx>>2, rows (idx&3)*64 + l.
  const unsigned short* pB0 =
      B + (size_t)(tn * 256 + ((2 * w) & 3) * 64 + l) * 2048 + ((2 * w) >> 2) * 8;
  const unsigned short* pB1 =
      B + (size_t)(tn * 256 + ((2 * w + 1) & 3) * 64 + l) * 2048 + ((2 * w + 1) >> 2) * 8;
  const int dA = w * 1024;
  const int dB0 = 8192 + (2 * w) * 1024;
  const int dB1 = 8192 + (2 * w + 1) * 1024;
  // per-lane LDS read offsets (add buf*24576 + kc*plane + mh/nh*512)
  const int aoff = hi * 2048 + (wr * 64 + l31) * 16;
  const int boff = 8192 + hi * 4096 + (wc * 64 + l31) * 16;

  f32x16 acc[2][2] = {};

#define STG(kt, bufs) do { if ((kt) < KT) {                                   \
    int kc_ = (kt) * 32;                                                      \
    gload16(pAl + kc_, Lp + (bufs) * 24576 + dA);                             \
    gload16(pB0 + kc_, Lp + (bufs) * 24576 + dB0);                            \
    gload16(pB1 + kc_, Lp + (bufs) * 24576 + dB1);                            \
  } } while (0)

#define GITER(kt, bufc, bufs, VM) do {                                        \
    STG((kt) + 2, bufs);                                                      \
    us8 af[2][2], bfr[2][2];                                                  \
    _Pragma("unroll") for (int kc = 0; kc < 2; ++kc) {                        \
      _Pragma("unroll") for (int mh = 0; mh < 2; ++mh)                        \
        af[kc][mh] = *(const us8*)(Lp + (bufc) * 24576 + kc * 4096 +          \
                                   mh * 512 + aoff);                          \
      _Pragma("unroll") for (int nh = 0; nh < 2; ++nh)                        \
        bfr[kc][nh] = *(const us8*)(Lp + (bufc) * 24576 + kc * 8192 +         \
                                    nh * 512 + boff);                         \
    }                                                                         \
    __builtin_amdgcn_s_setprio(1);                                            \
    _Pragma("unroll") for (int kc = 0; kc < 2; ++kc)                          \
    _Pragma("unroll") for (int mh = 0; mh < 2; ++mh)                          \
    _Pragma("unroll") for (int nh = 0; nh < 2; ++nh)                          \
      acc[mh][nh] = MFMA32(af[kc][mh], bfr[kc][nh], acc[mh][nh]);             \
    __builtin_amdgcn_s_setprio(0);                                            \
    asm volatile("s_waitcnt vmcnt(" #VM ")" ::: "memory");                    \
    __builtin_amdgcn_s_barrier();                                             \
    asm volatile("" ::: "memory");                                            \
  } while (0)

  // prologue: tiles 0,1 staged; VMW(3) confirms tile 0 (tile 1 in flight)
  STG(0, 0); STG(1, 1);
  asm volatile("s_waitcnt vmcnt(3)" ::: "memory");
  __builtin_amdgcn_s_barrier();
  asm volatile("" ::: "memory");

#pragma unroll 1
  for (int t3 = 0; t3 < 60; t3 += 3) {
    GITER(t3 + 0, 0, 2, 3);
    GITER(t3 + 1, 1, 0, 3);
    GITER(t3 + 2, 2, 1, 3);
  }
  GITER(60, 0, 2, 3);   // stages 62 -> b2
  GITER(61, 1, 0, 3);   // stages 63 -> b0
  GITER(62, 2, 1, 0);   // stage(64) skipped; VMW(0) drains tile 63
  GITER(63, 0, 2, 0);   // nothing outstanding

#undef GITER
#undef STG

  // epilogue: C/D mapping col=l31, row=(r&3)+8*(r>>2)+4*hi
#pragma unroll
  for (int mh = 0; mh < 2; ++mh)
#pragma unroll
  for (int nh = 0; nh < 2; ++nh) {
    int mb = tm * 128 + wr * 64 + mh * 32 + 4 * hi;
    if (EPI == 1) {
      int n = tn * 256 + wc * 64 + nh * 32 + l31;
      float bz = bias[n];
#pragma unroll
      for (int q = 0; q < 4; ++q)
#pragma unroll
        for (int j = 0; j < 4; ++j)
          outF[(size_t)(mb + 8 * q + j) * N + n] = acc[mh][nh][4 * q + j] + bz;
    } else {
      int n6 = tn * 256 + wc * 64 + nh * 32 + l31;
      int sel = n6 >> 11, d = n6 & 2047, h = d >> 7, hd = d & 127;
      int b = mb >> 11;
      if (sel == 2) {  // v -> transposed [bh][hd][S]
        float badd = bv[d];
#pragma unroll
        for (int q = 0; q < 4; ++q) {
          int s0 = (mb + 8 * q) & 2047;
          us4 pk;
#pragma unroll
          for (int j = 0; j < 4; ++j) pk[j] = f2bf(acc[mh][nh][4 * q + j] + badd);
          *(us4*)&vtb[((size_t)(b * 16 + h) * 128 + hd) * 2048 + s0] = pk;
        }
      } else {  // q/k -> [bh][S][hd]
        unsigned short* dst = sel ? kb : qb;
        float badd = sel ? 0.f : bq[d];
#pragma unroll
        for (int q = 0; q < 4; ++q) {
          int s0 = (mb + 8 * q) & 2047;
#pragma unroll
          for (int j = 0; j < 4; ++j)
            dst[((size_t)(b * 16 + h) * 2048 + (s0 + j)) * 128 + hd] =
                f2bf(acc[mh][nh][4 * q + j] + badd);
        }
      }
    }
  }
}

// ---------------- R2-verified 128x256 deep-prefetch GEMM (out-proj) ----------
template <int EPI>
__global__ __launch_bounds__(512, 2) void gemm2(
    const unsigned short* __restrict__ A, const unsigned short* __restrict__ B,
    int nTN, int N,
    float* __restrict__ outF, const float* __restrict__ bias) {
  constexpr int K = 2048, KT = 64;
  __shared__ alignas(16) char L[4 * 24576];
  int bid = (int)blockIdx.x, nwg = (int)gridDim.x;
  {
    int qq = nwg >> 3;
    int xcd = bid & 7, idx = bid >> 3;
    bid = xcd * qq + idx;
  }
  int tm = bid / nTN, tn = bid % nTN;
  int t = (int)threadIdx.x, l = t & 63, w = t >> 6;
  int g = l >> 4, ln = l & 15;
  int wr = w >> 2, wc = w & 3;
  const unsigned short* Ab =
      A + (size_t)(tm * 128 + w * 16 + (l >> 2)) * K + (l & 3) * 8;
  const unsigned short* Bb =
      B + (size_t)(tn * 256 + w * 16 + (l >> 2)) * K + (l & 3) * 8;
  f32x4 acc[4][4] = {};

#define STAGE(tile) do {                                                      \
    char* Lb = L + ((tile) & 3) * 24576 + w * 1024;                           \
    int kc = (tile) * 32;                                                     \
    gload16(Ab + kc, Lb);                                                     \
    gload16(Bb + kc, Lb + 8192);                                              \
    gload16(Bb + (size_t)128 * K + kc, Lb + 16384);                           \
  } while (0)

#define GITER(kt, VM) do {                                                    \
    asm volatile("s_waitcnt vmcnt(" #VM ")" ::: "memory");                    \
    __builtin_amdgcn_s_barrier();                                             \
    __builtin_amdgcn_sched_barrier(0);                                        \
    asm volatile("" ::: "memory");                                            \
    if ((kt) + 3 < KT) STAGE((kt) + 3);                                       \
    const unsigned short* Lc = (const unsigned short*)(L + ((kt) & 3) * 24576); \
    us8 af[4], bfr[4];                                                        \
    _Pragma("unroll") for (int mf = 0; mf < 4; ++mf)                          \
      af[mf] = *(const us8*)&Lc[(wr * 64 + mf * 16 + ln) * 32 + g * 8];       \
    _Pragma("unroll") for (int nf = 0; nf < 4; ++nf)                          \
      bfr[nf] = *(const us8*)&Lc[4096 + (wc * 64 + nf * 16 + ln) * 32 + g * 8]; \
    __builtin_amdgcn_s_setprio(1);                                            \
    _Pragma("unroll") for (int mf = 0; mf < 4; ++mf)                          \
      _Pragma("unroll") for (int nf = 0; nf < 4; ++nf)                        \
        acc[mf][nf] = MFMA16(af[mf], bfr[nf], acc[mf][nf]);                   \
    __builtin_amdgcn_s_setprio(0);                                            \
  } while (0)

  STAGE(0); STAGE(1); STAGE(2);
#pragma unroll 1
  for (int kt = 0; kt < KT - 2; ++kt) GITER(kt, 6);
  GITER(KT - 2, 3);
  GITER(KT - 1, 0);
#undef STAGE
#undef GITER

#pragma unroll
  for (int mf = 0; mf < 4; ++mf)
#pragma unroll
    for (int nf = 0; nf < 4; ++nf) {
      int n = tn * 256 + wc * 64 + nf * 16 + ln;
      float bz = bias[n];
#pragma unroll
      for (int r = 0; r < 4; ++r) {
        int m = tm * 128 + wr * 64 + mf * 16 + g * 4 + r;
        outF[(size_t)m * N + n] = acc[mf][nf][r] + bz;
      }
    }
}

// ---------------- interleaved RoPE on q,k in place ----------------
__global__ __launch_bounds__(256) void rope_k(u32* __restrict__ q, u32* __restrict__ k) {
  int idx = blockIdx.x * 256 + threadIdx.x;  // exactly 2*16*2048*64
  int i = idx & 63;
  int s = (idx >> 6) & 2047;
  float ang = (float)s * exp2f(-(float)i * 0.2076205059304703f);
  float sv, cv;
  sincosf(ang, &sv, &cv);
  u32 qu = q[idx];
  float a0 = bf2f((unsigned short)(qu & 0xffff)), a1 = bf2f((unsigned short)(qu >> 16));
  q[idx] = (u32)f2bf(a0 * cv - a1 * sv) | ((u32)f2bf(a1 * cv + a0 * sv) << 16);
  u32 ku = k[idx];
  float b0 = bf2f((unsigned short)(ku & 0xffff)), b1 = bf2f((unsigned short)(ku >> 16));
  k[idx] = (u32)f2bf(b0 * cv - b1 * sv) | ((u32)f2bf(b1 * cv + b0 * sv) << 16);
}

// ---------------- causal flash attention ----------------
__global__ __launch_bounds__(512) void attn_k(
    const unsigned short* __restrict__ qg, const unsigned short* __restrict__ kg,
    const unsigned short* __restrict__ vtg, unsigned short* __restrict__ ab) {
  __shared__ alignas(16) unsigned short Kl[64 * 128];   // [key][hd], swizzled
  __shared__ alignas(16) unsigned short Vl[128 * 64];   // [hd][key], swizzled
  __shared__ alignas(16) unsigned short Pl[8][16 * 72]; // per wave [qrow][key+pad]
  int bh = (int)blockIdx.x & 31;
  int pr = (int)blockIdx.x >> 5;
  int t = (int)threadIdx.x, l = t & 63, w = t >> 6;
  int g = l >> 4, ln = l & 15;
  int b = bh >> 4, h = bh & 15;
  const size_t bq0 = (size_t)bh * 2048 * 128;

#pragma unroll 1
  for (int half = 0; half < 2; ++half) {
    int qt = half ? 15 - pr : pr;
    int qbase = qt * 128;
    int qrow = qbase + w * 16 + ln;
    us8 qf[4];
#pragma unroll
    for (int kf = 0; kf < 4; ++kf)
      qf[kf] = *(const us8*)&qg[bq0 + (size_t)qrow * 128 + kf * 32 + g * 8];
    f32x4 o[8] = {};
    float mrow = -1e30f, lrow = 0.f;
    int nkt = (qbase >> 6) + 2;
#pragma unroll 1
    for (int kt = 0; kt < nkt; ++kt) {
      __syncthreads();
#pragma unroll
      for (int i = 0; i < 2; ++i) {
        int fb = i * 8192 + w * 1024;
        int flat = fb + l * 16;
        int row = flat >> 8, colb = flat & 255;
        int sc = colb ^ ((row & 7) << 4);  // pre-swizzled global source (m173)
        gload16(kg + (bq0 + (size_t)(kt * 64 + row) * 128 + (sc >> 1)), (char*)Kl + fb);
        int rv = flat >> 7, cv2 = flat & 127;
        int scv = cv2 ^ ((rv & 7) << 4);
        gload16(vtg + (bq0 + (size_t)rv * 2048 + kt * 64 + (scv >> 1)), (char*)Vl + fb);
      }
      __syncthreads();
      // S^T = K * Q^T : D[key_local][qrow_local]
      f32x4 st[4];
#pragma unroll
      for (int kfr = 0; kfr < 4; ++kfr) {
        f32x4 acc = {};
        int row = kfr * 16 + ln;
        int swz = (row & 7) << 4;
#pragma unroll
        for (int kf = 0; kf < 4; ++kf) {
          us8 kfrag = *(const us8*)((const char*)Kl + row * 256 + ((kf * 64 + g * 16) ^ swz));
          acc = MFMA16(kfrag, qf[kf], acc);
        }
        st[kfr] = acc;
      }
      float pmax = -1e30f;
#pragma unroll
      for (int kfr = 0; kfr < 4; ++kfr)
#pragma unroll
        for (int r = 0; r < 4; ++r) {
          int key = kt * 64 + kfr * 16 + g * 4 + r;
          float sv = key <= qrow ? st[kfr][r] * 0.08838834764831845f : -1e30f;
          st[kfr][r] = sv;
          pmax = fmaxf(pmax, sv);
        }
      pmax = fmaxf(pmax, __shfl_xor(pmax, 16));
      pmax = fmaxf(pmax, __shfl_xor(pmax, 32));
      if (__ballot(pmax > mrow + 8.f)) {
        float mnew = pmax > mrow + 8.f ? pmax : mrow;
        float corr = exp2f((mrow - mnew) * 1.44269504f);
        mrow = mnew;
        lrow *= corr;
#pragma unroll
        for (int r = 0; r < 4; ++r) {
          float cr = __shfl(corr, g * 4 + r);
#pragma unroll
          for (int nf = 0; nf < 8; ++nf) o[nf][r] *= cr;
        }
      }
      float lsum = 0.f;
#pragma unroll
      for (int kfr = 0; kfr < 4; ++kfr) {
        us4 pk;
#pragma unroll
        for (int r = 0; r < 4; ++r) {
          float p = exp2f((st[kfr][r] - mrow) * 1.44269504f);
          lsum += p;
          pk[r] = f2bf(p);
        }
        *(us4*)&Pl[w][ln * 72 + kfr * 16 + g * 4] = pk;
      }
      lsum += __shfl_xor(lsum, 16);
      lsum += __shfl_xor(lsum, 32);
      lrow += lsum;
#pragma unroll
      for (int kf2 = 0; kf2 < 2; ++kf2) {
        us8 pa = *(const us8*)&Pl[w][ln * 72 + kf2 * 32 + g * 8];
#pragma unroll
        for (int nf = 0; nf < 8; ++nf) {
          int row = nf * 16 + ln;
          us8 vb = *(const us8*)((const char*)Vl + row * 128 +
                                 ((kf2 * 64 + g * 16) ^ ((row & 7) << 4)));
          o[nf] = MFMA16(pa, vb, o[nf]);
        }
      }
    }  // kt
    float invl = 1.f / lrow;
#pragma unroll
    for (int r = 0; r < 4; ++r) {
      float ir = __shfl(invl, g * 4 + r);
      int srow = qbase + w * 16 + g * 4 + r;
      size_t base = ((size_t)b * 2048 + srow) * 2048 + h * 128 + ln;
#pragma unroll
      for (int nf = 0; nf < 8; ++nf) ab[base + (size_t)nf * 16] = f2bf(o[nf][r] * ir);
    }
  }  // half
}

extern "C" void kernel_launch(void* const* d_in, const int* in_sizes, int n_in,
                              void* d_out, int out_size, void* d_ws, size_t ws_size,
                              hipStream_t stream) {
  const float* x  = (const float*)d_in[0];
  const float* Wq = (const float*)d_in[1];
  const float* bq = (const float*)d_in[2];
  const float* Wk = (const float*)d_in[3];
  const float* Wv = (const float*)d_in[4];
  const float* bv = (const float*)d_in[5];
  const float* Wo = (const float*)d_in[6];
  const float* bo = (const float*)d_in[7];
  float* out = (float*)d_out;

  unsigned short* ws = (unsigned short*)d_ws;
  unsigned short* xb   = ws;                // 8388608 elems (x bf16; later reused as attn out)
  unsigned short* wcat = xb + 8388608;      // 12582912 (Wq|Wk|Wv rows, [6144][2048])
  unsigned short* wob  = wcat + 12582912;   // 4194304
  unsigned short* qb   = wob + 4194304;     // 8388608  [32][2048][128]
  unsigned short* kb   = qb + 8388608;      // 8388608
  unsigned short* vtb  = kb + 8388608;      // 8388608  [32][128][2048] (transposed)

  convert_all<<<2048, 256, 0, stream>>>(x, Wq, Wk, Wv, Wo, xb, wcat, wob);
  gemm32<0><<<768, 512, 0, stream>>>(xb, wcat, 24, 6144,
                                     nullptr, nullptr, qb, kb, vtb, bq, bv);
  rope_k<<<16384, 256, 0, stream>>>((u32*)qb, (u32*)kb);
  attn_k<<<256, 512, 0, stream>>>(qb, kb, vtb, xb /* a_buf alias */);
  gemm2<1><<<256, 512, 0, stream>>>(xb, wob, 8, 2048, out, bo);
}

// Round 7
// 275.579 us; speedup vs baseline: 1.2588x; 1.2588x over previous
//
#include <hip/hip_runtime.h>
#include <stdint.h>

typedef float f32x4 __attribute__((ext_vector_type(4)));
typedef __bf16 bf16x8 __attribute__((ext_vector_type(8)));
typedef unsigned short us8 __attribute__((ext_vector_type(8)));
typedef unsigned short us4 __attribute__((ext_vector_type(4)));
typedef unsigned int u32;

#define MFMA16(A, B, C) __builtin_amdgcn_mfma_f32_16x16x32_bf16( \
    __builtin_bit_cast(bf16x8, (A)), __builtin_bit_cast(bf16x8, (B)), (C), 0, 0, 0)

__device__ __forceinline__ unsigned short f2bf(float f) {
  u32 u = __builtin_bit_cast(u32, f);
  u = u + 0x7fffu + ((u >> 16) & 1u);   // RNE
  return (unsigned short)(u >> 16);
}
__device__ __forceinline__ float bf2f(unsigned short b) {
  u32 u = ((u32)b) << 16;
  return __builtin_bit_cast(float, u);
}
// async global->LDS, 16B per lane. LDS dest must be wave-uniform base (HW adds lane*16).
__device__ __forceinline__ void gload16(const void* g, void* lds) {
  __builtin_amdgcn_global_load_lds((const __attribute__((address_space(1))) u32*)g,
                                   (__attribute__((address_space(3))) u32*)lds, 16, 0, 0);
}

// ---------------- fp32 -> bf16 conversion of x and weights ----------------
__global__ __launch_bounds__(256) void convert_all(
    const float* __restrict__ x, const float* __restrict__ wq, const float* __restrict__ wk,
    const float* __restrict__ wv, const float* __restrict__ wo,
    unsigned short* __restrict__ xb, unsigned short* __restrict__ wcat,
    unsigned short* __restrict__ wob) {
  int tid = blockIdx.x * 256 + threadIdx.x;
  int nth = gridDim.x * 256;
  const float* srcs[5] = {x, wq, wk, wv, wo};
  unsigned short* dsts[5] = {xb, wcat, wcat + 4194304, wcat + 8388608, wob};
  const int n4s[5] = {2097152, 1048576, 1048576, 1048576, 1048576};
#pragma unroll
  for (int sg = 0; sg < 5; ++sg) {
    const float4* s = (const float4*)srcs[sg];
    us4* d = (us4*)dsts[sg];
    int n4 = n4s[sg];
    for (int i = tid; i < n4; i += nth) {
      float4 v = s[i];
      us4 o;
      o[0] = f2bf(v.x); o[1] = f2bf(v.y); o[2] = f2bf(v.z); o[3] = f2bf(v.w);
      d[i] = o;
    }
  }
}

// ------- 256x256 bf16 GEMM, C = A * B^T: row-major swizzled LDS (m201-faithful) ----
// BM=BN=256, BK=64, 512 thr = 8 waves (2M x 4N), per-wave 128x64 = acc[2][2][4][2].
// LDS 128KB: 2 buffers x { A[256][64], B[256][64] } row-major, elem (r,c) stored at
// byte r*128 + ((c*2) ^ ((r&7)<<4))  (G4 swizzle; reads spread 16-lane groups over
// 8 slots -> <=2-way aliasing = free).
// STAGING (the R7 fix): LDS dest linear (gload16 lane x 16B), inverse-permuted
// GLOBAL source: lane l -> row l>>3, col-slot (l&7)^(l>>3). Each 8-lane group reads
// one FULL 128B line (8 lines/instr, 100% util) vs 64 scattered lines before.
// Schedule (R5-verified skeleton): reads ph0 (A0,B0,B1) + ph2 (A1); stages for t+1:
// B calls 0,1@ph0  2,3@ph1  A calls 0,2@ph2  1,3@ph3.  Waits: vmcnt(4)@ph1-end
// (confirms A1,A3(t), leaves 4 B(t+1)), vmcnt(2)@ph3-end (confirms B+A0,A2(t+1),
// leaves A1,A3(t+1)). Never 0 until peeled tail.
template <int EPI>
__global__ __launch_bounds__(512, 2) void gemmsw(
    const unsigned short* __restrict__ A, const unsigned short* __restrict__ B,
    int nTN, int N,
    float* __restrict__ outF, const float* __restrict__ bias,
    unsigned short* __restrict__ qb, unsigned short* __restrict__ kb,
    unsigned short* __restrict__ vtb, const float* __restrict__ bq,
    const float* __restrict__ bv) {
  constexpr int KT = 32;  // K=2048 / BK=64
  __shared__ alignas(16) char L[131072];
  char* Lp = L;
  int bid = (int)blockIdx.x, nwg = (int)gridDim.x;
  {  // XCD-aware swizzle; grids are multiples of 8
    int qq = nwg >> 3;
    int xcd = bid & 7, idx = bid >> 3;
    bid = xcd * qq + idx;
  }
  int tm = bid / nTN, tn = bid % nTN;
  int t = (int)threadIdx.x, l = t & 63, w = t >> 6;
  int g = l >> 4, ln = l & 15;
  int wr = w >> 2, wc = w & 3;   // 2M x 4N wave grid
  // staging source: lane l -> row w*8 + (l>>3), col-slot (l&7)^(l>>3) (16B slots)
  int lr = l >> 3, lc = l & 7;
  int scol = lc ^ lr;
  const unsigned short* pAs = A + (size_t)(tm * 256 + w * 8 + lr) * 2048 + scol * 8;
  const unsigned short* pBs = B + (size_t)(tn * 256 + w * 8 + lr) * 2048 + scol * 8;

  f32x4 acc[2][2][4][2] = {};
  us8 af[4][2], bf[2][2][2];

#define FENCE asm volatile("" ::: "memory")
#define BAR do { FENCE; __builtin_amdgcn_s_barrier(); FENCE; } while (0)
#define VMW_(n) asm volatile("s_waitcnt vmcnt(" #n ")" ::: "memory")
#define VMW(n) VMW_(n)
// stage call i (rows i*64 + w*8 .. +8) of tile kt into buffer bufsel
#define STA(i, kt, bufsel) do { if ((kt) < KT)                                \
    gload16(pAs + (size_t)(i) * 131072 + (size_t)(kt) * 64,                   \
            Lp + (bufsel) * 65536 + (i) * 8192 + w * 1024); } while (0)
#define STB(i, kt, bufsel) do { if ((kt) < KT)                                \
    gload16(pBs + (size_t)(i) * 131072 + (size_t)(kt) * 64,                   \
            Lp + (bufsel) * 65536 + 32768 + (i) * 8192 + w * 1024); } while (0)
// frag reads: row r, k-elems kc*32+g*8..+8 -> byte r*128 + ((kc*64+g*16)^((r&7)<<4));
// r&7 == ln&7 for all frags (row bases are multiples of 8/16).
#define RD_A(mh_, bufsel) do {                                                \
    _Pragma("unroll") for (int mf = 0; mf < 4; ++mf)                          \
    _Pragma("unroll") for (int kc = 0; kc < 2; ++kc)                          \
      af[mf][kc] = *(const us8*)(Lp + (bufsel) * 65536 +                      \
          (wr * 128 + (mh_) * 64 + mf * 16 + ln) * 128 +                      \
          ((kc * 64 + g * 16) ^ ((ln & 7) << 4)));                            \
  } while (0)
#define RD_B(nh_, bufsel) do {                                                \
    _Pragma("unroll") for (int nf = 0; nf < 2; ++nf)                          \
    _Pragma("unroll") for (int kc = 0; kc < 2; ++kc)                          \
      bf[nh_][nf][kc] = *(const us8*)(Lp + (bufsel) * 65536 + 32768 +         \
          (wc * 64 + (nh_) * 32 + nf * 16 + ln) * 128 +                       \
          ((kc * 64 + g * 16) ^ ((ln & 7) << 4)));                            \
  } while (0)
#define MM(mh_, nh_) do {                                                     \
    __builtin_amdgcn_s_setprio(1);                                            \
    _Pragma("unroll") for (int mf = 0; mf < 4; ++mf)                          \
    _Pragma("unroll") for (int nf = 0; nf < 2; ++nf)                          \
    _Pragma("unroll") for (int kc = 0; kc < 2; ++kc)                          \
      acc[mh_][nh_][mf][nf] = MFMA16(af[mf][kc], bf[nh_][nf][kc],             \
                                     acc[mh_][nh_][mf][nf]);                  \
    __builtin_amdgcn_s_setprio(0);                                            \
  } while (0)
// Outstanding-count ledger (steady state, entering tile t with 2 = {A1,A3(t)}):
//  ph0: +STB0,1(t+1) -> 4;  ph1: +STB2,3 -> 6, VMW(4) confirms A1,A3(t);
//  ph2: +STA0,2 -> 6;       ph3: +STA1,3 -> 8, VMW(2) confirms B*,A0,A2(t+1).
#define TILE(kt, b, VM1, VM3) do {                                            \
  /*ph0*/ RD_A(0, b); RD_B(0, b); RD_B(1, b);                                 \
          STB(0, (kt) + 1, (b) ^ 1); STB(1, (kt) + 1, (b) ^ 1);               \
          BAR; MM(0, 0); BAR;                                                 \
  /*ph1*/ STB(2, (kt) + 1, (b) ^ 1); STB(3, (kt) + 1, (b) ^ 1);               \
          BAR; MM(0, 1); VMW(VM1); BAR;                                       \
  /*ph2*/ RD_A(1, b);                                                         \
          STA(0, (kt) + 1, (b) ^ 1); STA(2, (kt) + 1, (b) ^ 1);               \
          BAR; MM(1, 0); BAR;                                                 \
  /*ph3*/ STA(1, (kt) + 1, (b) ^ 1); STA(3, (kt) + 1, (b) ^ 1);               \
          MM(1, 1); VMW(VM3); BAR;                                            \
} while (0)

  // prologue: tile0 fully staged into buf0; full drain once (prologue only)
  STB(0, 0, 0); STB(1, 0, 0); STB(2, 0, 0); STB(3, 0, 0);
  STA(0, 0, 0); STA(2, 0, 0); STA(1, 0, 0); STA(3, 0, 0);
  VMW(0); BAR;

#pragma unroll 1
  for (int kt = 0; kt < 30; kt += 2) {
    TILE(kt, 0, 4, 2);
    TILE(kt + 1, 1, 4, 2);
  }
  TILE(30, 0, 4, 2);   // stages tile 31 into buf1
  TILE(31, 1, 0, 0);   // stage guards drop; VMW(0)@ph1 drains A1,A3(31)

#undef TILE
#undef MM
#undef RD_B
#undef RD_A
#undef STB
#undef STA
#undef VMW
#undef VMW_
#undef BAR
#undef FENCE

  if (EPI == 1) {
#pragma unroll
    for (int mh = 0; mh < 2; ++mh)
#pragma unroll
    for (int nh = 0; nh < 2; ++nh)
#pragma unroll
    for (int mf = 0; mf < 4; ++mf)
#pragma unroll
    for (int nf = 0; nf < 2; ++nf) {
      int n = tn * 256 + wc * 64 + nh * 32 + nf * 16 + ln;
      float bz = bias[n];
      int m0 = tm * 256 + wr * 128 + mh * 64 + mf * 16 + g * 4;
#pragma unroll
      for (int r = 0; r < 4; ++r)
        outF[(size_t)(m0 + r) * N + n] = acc[mh][nh][mf][nf][r] + bz;
    }
  } else {
#pragma unroll
    for (int mh = 0; mh < 2; ++mh)
#pragma unroll
    for (int nh = 0; nh < 2; ++nh)
#pragma unroll
    for (int mf = 0; mf < 4; ++mf)
#pragma unroll
    for (int nf = 0; nf < 2; ++nf) {
      int n6 = tn * 256 + wc * 64 + nh * 32 + nf * 16 + ln;
      int sel = n6 >> 11, d = n6 & 2047, h = d >> 7, hd = d & 127;
      int m0 = tm * 256 + wr * 128 + mh * 64 + mf * 16 + g * 4;
      int b = m0 >> 11, s0 = m0 & 2047;
      if (sel == 2) {  // v -> transposed [bh][hd][S]
        float badd = bv[d];
        us4 pk;
#pragma unroll
        for (int r = 0; r < 4; ++r) pk[r] = f2bf(acc[mh][nh][mf][nf][r] + badd);
        *(us4*)&vtb[((size_t)(b * 16 + h) * 128 + hd) * 2048 + s0] = pk;
      } else {  // q/k -> [bh][S][hd]
        unsigned short* dst = sel ? kb : qb;
        float badd = sel ? 0.f : bq[d];
#pragma unroll
        for (int r = 0; r < 4; ++r)
          dst[((size_t)(b * 16 + h) * 2048 + (s0 + r)) * 128 + hd] =
              f2bf(acc[mh][nh][mf][nf][r] + badd);
      }
    }
  }
}

// ---------------- R2-verified 128x256 deep-prefetch GEMM (out-proj) ----------
template <int EPI>
__global__ __launch_bounds__(512, 2) void gemm2(
    const unsigned short* __restrict__ A, const unsigned short* __restrict__ B,
    int nTN, int N,
    float* __restrict__ outF, const float* __restrict__ bias) {
  constexpr int K = 2048, KT = 64;
  __shared__ alignas(16) char L[4 * 24576];
  int bid = (int)blockIdx.x, nwg = (int)gridDim.x;
  {
    int qq = nwg >> 3;
    int xcd = bid & 7, idx = bid >> 3;
    bid = xcd * qq + idx;
  }
  int tm = bid / nTN, tn = bid % nTN;
  int t = (int)threadIdx.x, l = t & 63, w = t >> 6;
  int g = l >> 4, ln = l & 15;
  int wr = w >> 2, wc = w & 3;
  const unsigned short* Ab =
      A + (size_t)(tm * 128 + w * 16 + (l >> 2)) * K + (l & 3) * 8;
  const unsigned short* Bb =
      B + (size_t)(tn * 256 + w * 16 + (l >> 2)) * K + (l & 3) * 8;
  f32x4 acc[4][4] = {};

#define STAGE(tile) do {                                                      \
    char* Lb = L + ((tile) & 3) * 24576 + w * 1024;                           \
    int kc = (tile) * 32;                                                     \
    gload16(Ab + kc, Lb);                                                     \
    gload16(Bb + kc, Lb + 8192);                                              \
    gload16(Bb + (size_t)128 * K + kc, Lb + 16384);                           \
  } while (0)

#define GITER(kt, VM) do {                                                    \
    asm volatile("s_waitcnt vmcnt(" #VM ")" ::: "memory");                    \
    __builtin_amdgcn_s_barrier();                                             \
    __builtin_amdgcn_sched_barrier(0);                                        \
    asm volatile("" ::: "memory");                                            \
    if ((kt) + 3 < KT) STAGE((kt) + 3);                                       \
    const unsigned short* Lc = (const unsigned short*)(L + ((kt) & 3) * 24576); \
    us8 af[4], bfr[4];                                                        \
    _Pragma("unroll") for (int mf = 0; mf < 4; ++mf)                          \
      af[mf] = *(const us8*)&Lc[(wr * 64 + mf * 16 + ln) * 32 + g * 8];       \
    _Pragma("unroll") for (int nf = 0; nf < 4; ++nf)                          \
      bfr[nf] = *(const us8*)&Lc[4096 + (wc * 64 + nf * 16 + ln) * 32 + g * 8]; \
    __builtin_amdgcn_s_setprio(1);                                            \
    _Pragma("unroll") for (int mf = 0; mf < 4; ++mf)                          \
      _Pragma("unroll") for (int nf = 0; nf < 4; ++nf)                        \
        acc[mf][nf] = MFMA16(af[mf], bfr[nf], acc[mf][nf]);                   \
    __builtin_amdgcn_s_setprio(0);                                            \
  } while (0)

  STAGE(0); STAGE(1); STAGE(2);
#pragma unroll 1
  for (int kt = 0; kt < KT - 2; ++kt) GITER(kt, 6);
  GITER(KT - 2, 3);
  GITER(KT - 1, 0);
#undef STAGE
#undef GITER

#pragma unroll
  for (int mf = 0; mf < 4; ++mf)
#pragma unroll
    for (int nf = 0; nf < 4; ++nf) {
      int n = tn * 256 + wc * 64 + nf * 16 + ln;
      float bz = bias[n];
#pragma unroll
      for (int r = 0; r < 4; ++r) {
        int m = tm * 128 + wr * 64 + mf * 16 + g * 4 + r;
        outF[(size_t)m * N + n] = acc[mf][nf][r] + bz;
      }
    }
}

// ---------------- interleaved RoPE on q,k in place ----------------
__global__ __launch_bounds__(256) void rope_k(u32* __restrict__ q, u32* __restrict__ k) {
  int idx = blockIdx.x * 256 + threadIdx.x;  // exactly 2*16*2048*64
  int i = idx & 63;
  int s = (idx >> 6) & 2047;
  float ang = (float)s * exp2f(-(float)i * 0.2076205059304703f);
  float sv, cv;
  sincosf(ang, &sv, &cv);
  u32 qu = q[idx];
  float a0 = bf2f((unsigned short)(qu & 0xffff)), a1 = bf2f((unsigned short)(qu >> 16));
  q[idx] = (u32)f2bf(a0 * cv - a1 * sv) | ((u32)f2bf(a1 * cv + a0 * sv) << 16);
  u32 ku = k[idx];
  float b0 = bf2f((unsigned short)(ku & 0xffff)), b1 = bf2f((unsigned short)(ku >> 16));
  k[idx] = (u32)f2bf(b0 * cv - b1 * sv) | ((u32)f2bf(b1 * cv + b0 * sv) << 16);
}

// ---------------- causal flash attention ----------------
__global__ __launch_bounds__(512) void attn_k(
    const unsigned short* __restrict__ qg, const unsigned short* __restrict__ kg,
    const unsigned short* __restrict__ vtg, unsigned short* __restrict__ ab) {
  __shared__ alignas(16) unsigned short Kl[64 * 128];   // [key][hd], swizzled
  __shared__ alignas(16) unsigned short Vl[128 * 64];   // [hd][key], swizzled
  __shared__ alignas(16) unsigned short Pl[8][16 * 72]; // per wave [qrow][key+pad]
  int bh = (int)blockIdx.x & 31;
  int pr = (int)blockIdx.x >> 5;
  int t = (int)threadIdx.x, l = t & 63, w = t >> 6;
  int g = l >> 4, ln = l & 15;
  int b = bh >> 4, h = bh & 15;
  const size_t bq0 = (size_t)bh * 2048 * 128;

#pragma unroll 1
  for (int half = 0; half < 2; ++half) {
    int qt = half ? 15 - pr : pr;
    int qbase = qt * 128;
    int qrow = qbase + w * 16 + ln;
    us8 qf[4];
#pragma unroll
    for (int kf = 0; kf < 4; ++kf)
      qf[kf] = *(const us8*)&qg[bq0 + (size_t)qrow * 128 + kf * 32 + g * 8];
    f32x4 o[8] = {};
    float mrow = -1e30f, lrow = 0.f;
    int nkt = (qbase >> 6) + 2;
#pragma unroll 1
    for (int kt = 0; kt < nkt; ++kt) {
      __syncthreads();
#pragma unroll
      for (int i = 0; i < 2; ++i) {
        int fb = i * 8192 + w * 1024;
        int flat = fb + l * 16;
        int row = flat >> 8, colb = flat & 255;
        int sc = colb ^ ((row & 7) << 4);  // pre-swizzled global source (m173)
        gload16(kg + (bq0 + (size_t)(kt * 64 + row) * 128 + (sc >> 1)), (char*)Kl + fb);
        int rv = flat >> 7, cv2 = flat & 127;
        int scv = cv2 ^ ((rv & 7) << 4);
        gload16(vtg + (bq0 + (size_t)rv * 2048 + kt * 64 + (scv >> 1)), (char*)Vl + fb);
      }
      __syncthreads();
      // S^T = K * Q^T : D[key_local][qrow_local]
      f32x4 st[4];
#pragma unroll
      for (int kfr = 0; kfr < 4; ++kfr) {
        f32x4 acc = {};
        int row = kfr * 16 + ln;
        int swz = (row & 7) << 4;
#pragma unroll
        for (int kf = 0; kf < 4; ++kf) {
          us8 kfrag = *(const us8*)((const char*)Kl + row * 256 + ((kf * 64 + g * 16) ^ swz));
          acc = MFMA16(kfrag, qf[kf], acc);
        }
        st[kfr] = acc;
      }
      float pmax = -1e30f;
#pragma unroll
      for (int kfr = 0; kfr < 4; ++kfr)
#pragma unroll
        for (int r = 0; r < 4; ++r) {
          int key = kt * 64 + kfr * 16 + g * 4 + r;
          float sv = key <= qrow ? st[kfr][r] * 0.08838834764831845f : -1e30f;
          st[kfr][r] = sv;
          pmax = fmaxf(pmax, sv);
        }
      pmax = fmaxf(pmax, __shfl_xor(pmax, 16));
      pmax = fmaxf(pmax, __shfl_xor(pmax, 32));
      if (__ballot(pmax > mrow + 8.f)) {
        float mnew = pmax > mrow + 8.f ? pmax : mrow;
        float corr = exp2f((mrow - mnew) * 1.44269504f);
        mrow = mnew;
        lrow *= corr;
#pragma unroll
        for (int r = 0; r < 4; ++r) {
          float cr = __shfl(corr, g * 4 + r);
#pragma unroll
          for (int nf = 0; nf < 8; ++nf) o[nf][r] *= cr;
        }
      }
      float lsum = 0.f;
#pragma unroll
      for (int kfr = 0; kfr < 4; ++kfr) {
        us4 pk;
#pragma unroll
        for (int r = 0; r < 4; ++r) {
          float p = exp2f((st[kfr][r] - mrow) * 1.44269504f);
          lsum += p;
          pk[r] = f2bf(p);
        }
        *(us4*)&Pl[w][ln * 72 + kfr * 16 + g * 4] = pk;
      }
      lsum += __shfl_xor(lsum, 16);
      lsum += __shfl_xor(lsum, 32);
      lrow += lsum;
#pragma unroll
      for (int kf2 = 0; kf2 < 2; ++kf2) {
        us8 pa = *(const us8*)&Pl[w][ln * 72 + kf2 * 32 + g * 8];
#pragma unroll
        for (int nf = 0; nf < 8; ++nf) {
          int row = nf * 16 + ln;
          us8 vb = *(const us8*)((const char*)Vl + row * 128 +
                                 ((kf2 * 64 + g * 16) ^ ((row & 7) << 4)));
          o[nf] = MFMA16(pa, vb, o[nf]);
        }
      }
    }  // kt
    float invl = 1.f / lrow;
#pragma unroll
    for (int r = 0; r < 4; ++r) {
      float ir = __shfl(invl, g * 4 + r);
      int srow = qbase + w * 16 + g * 4 + r;
      size_t base = ((size_t)b * 2048 + srow) * 2048 + h * 128 + ln;
#pragma unroll
      for (int nf = 0; nf < 8; ++nf) ab[base + (size_t)nf * 16] = f2bf(o[nf][r] * ir);
    }
  }  // half
}

extern "C" void kernel_launch(void* const* d_in, const int* in_sizes, int n_in,
                              void* d_out, int out_size, void* d_ws, size_t ws_size,
                              hipStream_t stream) {
  const float* x  = (const float*)d_in[0];
  const float* Wq = (const float*)d_in[1];
  const float* bq = (const float*)d_in[2];
  const float* Wk = (const float*)d_in[3];
  const float* Wv = (const float*)d_in[4];
  const float* bv = (const float*)d_in[5];
  const float* Wo = (const float*)d_in[6];
  const float* bo = (const float*)d_in[7];
  float* out = (float*)d_out;

  unsigned short* ws = (unsigned short*)d_ws;
  unsigned short* xb   = ws;                // 8388608 elems (x bf16; later reused as attn out)
  unsigned short* wcat = xb + 8388608;      // 12582912 (Wq|Wk|Wv rows, [6144][2048])
  unsigned short* wob  = wcat + 12582912;   // 4194304
  unsigned short* qb   = wob + 4194304;     // 8388608  [32][2048][128]
  unsigned short* kb   = qb + 8388608;      // 8388608
  unsigned short* vtb  = kb + 8388608;      // 8388608  [32][128][2048] (transposed)

  convert_all<<<2048, 256, 0, stream>>>(x, Wq, Wk, Wv, Wo, xb, wcat, wob);
  gemmsw<0><<<384, 512, 0, stream>>>(xb, wcat, 24, 6144,
                                     nullptr, nullptr, qb, kb, vtb, bq, bv);
  rope_k<<<16384, 256, 0, stream>>>((u32*)qb, (u32*)kb);
  attn_k<<<256, 512, 0, stream>>>(qb, kb, vtb, xb /* a_buf alias */);
  gemm2<1><<<256, 512, 0, stream>>>(xb, wob, 8, 2048, out, bo);
}